// Round 7
// baseline (309.434 us; speedup 1.0000x reference)
//
#include <hip/hip_runtime.h>
#include <hip/hip_bf16.h>

// DecoderLSTM: B=256, S=512, H=512, E=256, V=16000
#define B_ 256
#define S_ 512
#define H_ 512
#define E_ 256
#define V_ 16000

typedef __attribute__((ext_vector_type(4))) float f32x4_t;
typedef __attribute__((ext_vector_type(2))) float f32x2_t;
typedef __attribute__((ext_vector_type(8))) short bf16x8_t;
typedef __attribute__((ext_vector_type(2))) unsigned u32x2_t;

#define W2_SCALE 64.0f
#define W2_INV   0.015625f

__device__ __forceinline__ short f2bf(float f) {
    union { float f; unsigned u; } v; v.f = f;
    unsigned r = v.u + 0x7fffu + ((v.u >> 16) & 1u);   // RNE
    return (short)(r >> 16);
}

__device__ __forceinline__ float bf2f(short s) {
    union { unsigned u; float f; } v; v.u = ((unsigned)(unsigned short)s) << 16;
    return v.f;
}

__device__ __forceinline__ void cvt8(short* dst, const float* src) {
    f32x4_t a = *(const f32x4_t*)src;
    f32x4_t b = *(const f32x4_t*)(src + 4);
    bf16x8_t o;
    o[0] = f2bf(a[0]); o[1] = f2bf(a[1]); o[2] = f2bf(a[2]); o[3] = f2bf(a[3]);
    o[4] = f2bf(b[0]); o[5] = f2bf(b[1]); o[6] = f2bf(b[2]); o[7] = f2bf(b[3]);
    *(bf16x8_t*)dst = o;
}

__device__ __forceinline__ bf16x8_t pack8(f32x4_t a, f32x4_t b) {
    bf16x8_t o;
    o[0] = f2bf(a[0]); o[1] = f2bf(a[1]); o[2] = f2bf(a[2]); o[3] = f2bf(a[3]);
    o[4] = f2bf(b[0]); o[5] = f2bf(b[1]); o[6] = f2bf(b[2]); o[7] = f2bf(b[3]);
    return o;
}

// 8 fp8(e4m3) packed in 2 dwords -> bf16x8 (exact: e4m3 -> f32 -> bf16 lossless)
__device__ __forceinline__ bf16x8_t fp8x8_to_bf16x8(u32x2_t r) {
    f32x2_t f0 = __builtin_amdgcn_cvt_pk_f32_fp8(r[0], false);
    f32x2_t f1 = __builtin_amdgcn_cvt_pk_f32_fp8(r[0], true);
    f32x2_t f2 = __builtin_amdgcn_cvt_pk_f32_fp8(r[1], false);
    f32x2_t f3 = __builtin_amdgcn_cvt_pk_f32_fp8(r[1], true);
    union { unsigned u[4]; bf16x8_t v; } o;
    {
        float a = f0[0], b = f0[1];
        asm("v_cvt_pk_bf16_f32 %0, %1, %2" : "=v"(o.u[0]) : "v"(a), "v"(b));
    }
    {
        float a = f1[0], b = f1[1];
        asm("v_cvt_pk_bf16_f32 %0, %1, %2" : "=v"(o.u[1]) : "v"(a), "v"(b));
    }
    {
        float a = f2[0], b = f2[1];
        asm("v_cvt_pk_bf16_f32 %0, %1, %2" : "=v"(o.u[2]) : "v"(a), "v"(b));
    }
    {
        float a = f3[0], b = f3[1];
        asm("v_cvt_pk_bf16_f32 %0, %1, %2" : "=v"(o.u[3]) : "v"(a), "v"(b));
    }
    return o.v;
}

__device__ __forceinline__ float fast_tanh(float x) {
    float xc = fminf(8.f, fmaxf(-8.f, x));
    float e = __expf(2.f * xc);
    return (e - 1.f) / (e + 1.f);
}

// LDS chunk swizzle: row has 64 16B-chunks; interleave chunk bits + XOR row.
// bank-group of (c,r) is (c>>3)^(r&7) after swizzle.
__device__ __forceinline__ int physc(int c, int r) {
    return ((((c & 7) << 3) | (c >> 3)) ^ (r & 7));
}

// ---------------------------------------------------------------------------
// pack_w2: attn_W second half (W2), scaled x64 -> fragment-ordered FP8 e4m3.
// chunk c = ((kk*8 + wn)*4 + nf)*64 + lane holds 8 fp8 (2 dwords) of
//   W2[col = wn*64+nf*16+(lane&15)][k = kk*32+(lane>>4)*8 + j] * 64
// ---------------------------------------------------------------------------
__global__ void pack_w2(const float* __restrict__ attn_W, unsigned* __restrict__ Bp)
{
    const int c    = blockIdx.x * 256 + threadIdx.x;       // 32768 chunks
    const int lane = c & 63;
    const int nf   = (c >> 6) & 3;
    const int wn   = (c >> 8) & 7;
    const int kk   = c >> 11;                              // 0..15
    const int col  = wn * 64 + nf * 16 + (lane & 15);
    const int k    = kk * 32 + (lane >> 4) * 8;
    const float* src = attn_W + (size_t)col * (2 * H_) + H_ + k;
    f32x4_t a = *(const f32x4_t*)src;
    f32x4_t b = *(const f32x4_t*)(src + 4);
    unsigned lo = 0, hi = 0;
    lo = __builtin_amdgcn_cvt_pk_fp8_f32(a[0] * W2_SCALE, a[1] * W2_SCALE, lo, false);
    lo = __builtin_amdgcn_cvt_pk_fp8_f32(a[2] * W2_SCALE, a[3] * W2_SCALE, lo, true);
    hi = __builtin_amdgcn_cvt_pk_fp8_f32(b[0] * W2_SCALE, b[1] * W2_SCALE, hi, false);
    hi = __builtin_amdgcn_cvt_pk_fp8_f32(b[2] * W2_SCALE, b[3] * W2_SCALE, hi, true);
    u32x2_t st; st[0] = lo; st[1] = hi;
    *(u32x2_t*)(Bp + (size_t)c * 2) = st;
}

// ---------------------------------------------------------------------------
// bias1: h @ W1^T + attn_b.  128 blocks x 512 thr, 2 batches per block.
// ---------------------------------------------------------------------------
__global__ void bias1_kernel(const float* __restrict__ hidden,
                             const float* __restrict__ attn_W,
                             const float* __restrict__ attn_b,
                             float* __restrict__ bias1)
{
    const int t  = threadIdx.x;                // output col
    const int b0 = blockIdx.x * 2;
    __shared__ float h_s[2][512];
    h_s[0][t] = hidden[(size_t)b0 * H_ + t];
    h_s[1][t] = hidden[(size_t)(b0 + 1) * H_ + t];
    __syncthreads();
    const float* wrow = attn_W + (size_t)t * (2 * H_);     // W1 part: cols 0..511
    float a0 = 0.f, a1 = 0.f;
#pragma unroll 4
    for (int k = 0; k < 512; k += 4) {
        f32x4_t wv = *(const f32x4_t*)(wrow + k);
        a0 = fmaf(wv[0], h_s[0][k],     a0);
        a0 = fmaf(wv[1], h_s[0][k + 1], a0);
        a0 = fmaf(wv[2], h_s[0][k + 2], a0);
        a0 = fmaf(wv[3], h_s[0][k + 3], a0);
        a1 = fmaf(wv[0], h_s[1][k],     a1);
        a1 = fmaf(wv[1], h_s[1][k + 1], a1);
        a1 = fmaf(wv[2], h_s[1][k + 2], a1);
        a1 = fmaf(wv[3], h_s[1][k + 3], a1);
    }
    const float bb = attn_b[t];
    bias1[(size_t)b0 * H_ + t]       = a0 + bb;
    bias1[(size_t)(b0 + 1) * H_ + t] = a1 + bb;
}

// ---------------------------------------------------------------------------
// fused_attn: 512 blocks (2 per batch, each half the s-range = 4 tiles of 64).
// 512 threads / 8 waves. amdgpu_waves_per_eu(4,4): metadata 4 -> HW keeps
// 4 waves/EU = 2 blocks/CU co-resident (r5/r6 A/B: occupancy tracks this
// metadata value); max=4 keeps VGPR cap at 128 so acc does NOT spill
// (single-arg (4) squeezed to 64 VGPR and spilled, round 5).
// B = W2 packed as fp8 e4m3 (x64), converted fp8->bf16 in registers: halves
// the B-bytes-from-L2 per K-step (the measured structural bound, ~585 cyc
// vs 160 cyc MFMA), conversion rides the separate VALU pipe.
// Per tile: stage enc f32->bf16 swizzled LDS; MFMA energy GEMM (wave owns
// 64 cols); tanh+v reduce -> e = exp(score); ctx accumulated in registers.
// Outputs partial e / l / ctx (combine normalizes; |score|<=22.6 so exp
// needs no max-subtraction).
// ---------------------------------------------------------------------------
__global__ __launch_bounds__(512) __attribute__((amdgpu_waves_per_eu(4, 4)))
void fused_attn(const float* __restrict__ enc,
                const unsigned* __restrict__ Bp,
                const float* __restrict__ bias1,
                const float* __restrict__ vvec,
                float* __restrict__ e_ws,
                float* __restrict__ lpart,
                float* __restrict__ ctxpart)
{
    __shared__ short buf[64 * 512];          // 64 KB, swizzled chunks
    __shared__ float bias_s[512];
    __shared__ float v_s[512];
    __shared__ float e_loc[256];
    __shared__ float red[64][9];
    __shared__ float wred[4];

    const int t    = threadIdx.x;
    const int lane = t & 63;
    const int w    = t >> 6;                 // 0..7, col group (64 cols)
    const int b    = blockIdx.x >> 1;
    const int half = blockIdx.x & 1;

    bias_s[t] = bias1[(size_t)b * H_ + t];
    v_s[t]    = vvec[t];

    // staging assignment: row srow (0..63), col group scg (8 chunks)
    const int srow = t >> 3;
    const int scg  = t & 7;
    const float* gbase = enc + ((size_t)b * S_ + half * 256 + srow) * H_ + scg * 64;

    // ctx assignment (bank-uniform): chunk cc=(lane&7)*8+w, rows r == lane>>3 (mod 8)
    const int cg  = lane >> 3;                       // row residue
    const int cc  = (lane & 7) * 8 + w;              // chunk 0..63
    float acc8[8];
#pragma unroll
    for (int j = 0; j < 8; ++j) acc8[j] = 0.f;

    for (int tile = 0; tile < 4; ++tile) {
        // ---- stage tile into buf (f32 -> bf16, swizzled)
        const float* gp = gbase + (size_t)tile * 64 * H_;
#pragma unroll
        for (int i = 0; i < 8; ++i) {
            f32x4_t a = *(const f32x4_t*)(gp + i * 8);
            f32x4_t c = *(const f32x4_t*)(gp + i * 8 + 4);
            *(bf16x8_t*)&buf[srow * 512 + physc(scg * 8 + i, srow) * 8] = pack8(a, c);
        }
        __syncthreads();                      // staging visible

        // ---- energy GEMM: 64 rows x 64 cols (this wave) x K=512
        f32x4_t acc[4][4];
#pragma unroll
        for (int mf = 0; mf < 4; ++mf)
#pragma unroll
            for (int nf = 0; nf < 4; ++nf)
                acc[mf][nf] = (f32x4_t){0.f, 0.f, 0.f, 0.f};

#pragma unroll 4
        for (int kk = 0; kk < 16; ++kk) {
            const unsigned* bb = Bp + ((size_t)((kk * 8 + w) * 4) * 64 + lane) * 2;
            u32x2_t braw[4];
#pragma unroll
            for (int nf = 0; nf < 4; ++nf)
                braw[nf] = *(const u32x2_t*)(bb + nf * 128);
            bf16x8_t af[4];
            const int cpr = kk * 4 + (lane >> 4);
#pragma unroll
            for (int mf = 0; mf < 4; ++mf) {
                const int rl = mf * 16 + (lane & 15);
                af[mf] = *(const bf16x8_t*)&buf[rl * 512 + physc(cpr, rl) * 8];
            }
#pragma unroll
            for (int nfp = 0; nfp < 2; ++nfp) {
                bf16x8_t bfr0 = fp8x8_to_bf16x8(braw[2 * nfp]);
                bf16x8_t bfr1 = fp8x8_to_bf16x8(braw[2 * nfp + 1]);
                __builtin_amdgcn_s_setprio(1);
#pragma unroll
                for (int mf = 0; mf < 4; ++mf) {
                    acc[mf][2 * nfp]     = __builtin_amdgcn_mfma_f32_16x16x32_bf16(af[mf], bfr0, acc[mf][2 * nfp],     0, 0, 0);
                    acc[mf][2 * nfp + 1] = __builtin_amdgcn_mfma_f32_16x16x32_bf16(af[mf], bfr1, acc[mf][2 * nfp + 1], 0, 0, 0);
                }
                __builtin_amdgcn_s_setprio(0);
            }
        }

        // ---- epilogue: per-wave partial score over its 64 cols
        float part[16];
#pragma unroll
        for (int i = 0; i < 16; ++i) part[i] = 0.f;
#pragma unroll
        for (int nf = 0; nf < 4; ++nf) {
            const int col = w * 64 + nf * 16 + (lane & 15);
            const float bbv = bias_s[col];
            const float vl  = v_s[col];
#pragma unroll
            for (int mf = 0; mf < 4; ++mf)
#pragma unroll
                for (int r = 0; r < 4; ++r)
                    part[mf * 4 + r] += vl * fast_tanh(fmaf(acc[mf][nf][r], W2_INV, bbv));
        }
#pragma unroll
        for (int i = 0; i < 16; ++i) {
            float p = part[i];
            p += __shfl_xor(p, 1);
            p += __shfl_xor(p, 2);
            p += __shfl_xor(p, 4);
            p += __shfl_xor(p, 8);
            part[i] = p;
        }
        if ((lane & 15) == 0) {
#pragma unroll
            for (int mf = 0; mf < 4; ++mf)
#pragma unroll
                for (int r = 0; r < 4; ++r)
                    red[mf * 16 + ((lane >> 4) << 2) + r][w] = part[mf * 4 + r];
        }
        __syncthreads();                      // red visible

        if (t < 64) {
            float s = red[t][0] + red[t][1] + red[t][2] + red[t][3]
                    + red[t][4] + red[t][5] + red[t][6] + red[t][7];
            e_loc[tile * 64 + t] = __expf(s);
        }
        __syncthreads();                      // e_loc visible

        // ---- context accumulate: rows r = i*8+cg, chunk cc (bank-uniform)
#pragma unroll
        for (int i = 0; i < 8; ++i) {
            const int r   = i * 8 + cg;
            const float e = e_loc[tile * 64 + r];
            bf16x8_t ch = *(const bf16x8_t*)&buf[r * 512 + physc(cc, r) * 8];
#pragma unroll
            for (int j = 0; j < 8; ++j)
                acc8[j] = fmaf(e, bf2f(ch[j]), acc8[j]);
        }
        __syncthreads();                      // ctx reads done before next stage
    }

    // ---- ctx partial: reduce over cg (lanes differing in bits 3..5)
#pragma unroll
    for (int m = 8; m < 64; m <<= 1)
#pragma unroll
        for (int j = 0; j < 8; ++j)
            acc8[j] += __shfl_xor(acc8[j], m);
    ctxpart[(size_t)blockIdx.x * H_ + cc * 8 + cg] = acc8[cg];

    // ---- l partial + e out
    if (t < 256) {
        float sv = e_loc[t];
#pragma unroll
        for (int off = 32; off; off >>= 1) sv += __shfl_xor(sv, off);
        if (lane == 0) wred[w] = sv;
        e_ws[(size_t)b * S_ + half * 256 + t] = e_loc[t];
    }
    __syncthreads();
    if (t == 0)
        lpart[blockIdx.x] = wred[0] + wred[1] + wred[2] + wred[3];
}

// ---------------------------------------------------------------------------
// combine: normalize softmax pieces from the two half-S blocks.
// ---------------------------------------------------------------------------
__global__ void combine_kernel(const float* __restrict__ e_ws,
                               const float* __restrict__ lpart,
                               const float* __restrict__ ctxpart,
                               float* __restrict__ out_attn,
                               short* __restrict__ x_cat)
{
    const int b = blockIdx.x, t = threadIdx.x;          // 512 threads
    const float li = 1.f / (lpart[2 * b] + lpart[2 * b + 1]);
    out_attn[(size_t)b * S_ + t] = e_ws[(size_t)b * S_ + t] * li;
    const float ctx = ctxpart[(size_t)(2 * b) * H_ + t]
                    + ctxpart[(size_t)(2 * b + 1) * H_ + t];
    x_cat[(size_t)b * 1280 + 256 + t] = f2bf(ctx * li);
}

// ---------------------------------------------------------------------------
// gemm_std: BM=128, BN=128, BK=32, 4 waves (256 thr). A is pre-converted bf16.
// KIND 0 (gates): K=1280, N=2048, B = [W_ih | W_hh] rows, bias = b_ih+b_hh
// KIND 1 (pred):  K=512,  N=16000, B = fc_W rows,        bias = fc_b
// ---------------------------------------------------------------------------
template<int KIND>
__global__ __launch_bounds__(256, 2)
void gemm_std(const short* __restrict__ Abf,
              const float* __restrict__ B0,
              const float* __restrict__ B1,
              const float* __restrict__ bias0,
              const float* __restrict__ bias1v,
              float* __restrict__ out)
{
    constexpr int K = (KIND == 0) ? 1280 : 512;
    constexpr int N = (KIND == 0) ? 2048 : 16000;

    __shared__ short As[128 * 40];
    __shared__ short Bs[128 * 40];

    const int t    = threadIdx.x;
    const int lane = t & 63;
    const int w    = t >> 6;
    const int wm   = w >> 1;
    const int wn   = w & 1;
    const int row0 = blockIdx.x * 128;
    const int col0 = blockIdx.y * 128;

    f32x4_t acc[4][4];
#pragma unroll
    for (int i = 0; i < 4; ++i)
#pragma unroll
        for (int j = 0; j < 4; ++j)
            acc[i][j] = (f32x4_t){0.f, 0.f, 0.f, 0.f};

    const int arow = t >> 1, ah = (t & 1) * 16;
    const int bcol = t >> 1, bh = (t & 1) * 16;

    for (int ks = 0; ks < K / 32; ++ks) {
        const int k0 = ks * 32;
        __syncthreads();
        const short* asrc = Abf + (size_t)(row0 + arow) * K + k0 + ah;
        *(bf16x8_t*)&As[arow * 40 + ah]     = *(const bf16x8_t*)asrc;
        *(bf16x8_t*)&As[arow * 40 + ah + 8] = *(const bf16x8_t*)(asrc + 8);
        const float* bsrc;
        if constexpr (KIND == 0) {
            const int cg = col0 + bcol;
            bsrc = (k0 < 768) ? (B0 + (size_t)cg * 768 + k0 + bh)
                              : (B1 + (size_t)cg * 512 + (k0 - 768) + bh);
        } else {
            bsrc = B0 + (size_t)(col0 + bcol) * 512 + k0 + bh;
        }
        cvt8(&Bs[bcol * 40 + bh],     bsrc);
        cvt8(&Bs[bcol * 40 + bh + 8], bsrc + 8);
        __syncthreads();

        bf16x8_t af[4], bfr[4];
        const int ka = (lane >> 4) * 8;
#pragma unroll
        for (int mf = 0; mf < 4; ++mf)
            af[mf] = *(const bf16x8_t*)&As[(wm * 64 + mf * 16 + (lane & 15)) * 40 + ka];
#pragma unroll
        for (int nf = 0; nf < 4; ++nf)
            bfr[nf] = *(const bf16x8_t*)&Bs[(wn * 64 + nf * 16 + (lane & 15)) * 40 + ka];
#pragma unroll
        for (int mf = 0; mf < 4; ++mf)
#pragma unroll
            for (int nf = 0; nf < 4; ++nf)
                acc[mf][nf] = __builtin_amdgcn_mfma_f32_16x16x32_bf16(
                    af[mf], bfr[nf], acc[mf][nf], 0, 0, 0);
    }

#pragma unroll
    for (int mf = 0; mf < 4; ++mf)
#pragma unroll
        for (int nf = 0; nf < 4; ++nf) {
            const int col  = col0 + wn * 64 + nf * 16 + (lane & 15);
            const int rowb = row0 + wm * 64 + mf * 16 + ((lane >> 4) << 2);
            float bb;
            if constexpr (KIND == 0) bb = bias0[col] + bias1v[col];
            else                     bb = bias0[col];
#pragma unroll
            for (int r = 0; r < 4; ++r)
                out[(size_t)(rowb + r) * N + col] = acc[mf][nf][r] + bb;
        }
}

// ---------------------------------------------------------------------------
// small kernels
// ---------------------------------------------------------------------------
__global__ void prep_kernel(const int* __restrict__ tgt,
                            const float* __restrict__ emb,
                            const float* __restrict__ hidden,
                            short* __restrict__ x_cat)
{
    const int b = blockIdx.x, t = threadIdx.x;          // 256 threads
    const int tok = tgt[b];
    x_cat[(size_t)b * 1280 + t]             = f2bf(emb[(size_t)tok * E_ + t]);
    x_cat[(size_t)b * 1280 + 768 + t]       = f2bf(hidden[(size_t)b * H_ + t]);
    x_cat[(size_t)b * 1280 + 768 + 256 + t] = f2bf(hidden[(size_t)b * H_ + 256 + t]);
}

__global__ void lstm_kernel(const float* __restrict__ gates,
                            const float* __restrict__ cell,
                            float* __restrict__ out_h,
                            float* __restrict__ out_c,
                            short* __restrict__ h_bf)
{
    const int b = blockIdx.x, t = threadIdx.x;          // 512 threads
    const float* g = gates + (size_t)b * 2048;
    const float gi = g[t], gf = g[512 + t], gg = g[1024 + t], go = g[1536 + t];
    const float c  = cell[(size_t)b * H_ + t];
    const float si = 1.f / (1.f + __expf(-gi));
    const float sf = 1.f / (1.f + __expf(-gf));
    const float so = 1.f / (1.f + __expf(-go));
    const float cn = sf * c + si * tanhf(gg);
    const float hn = so * tanhf(cn);
    out_h[(size_t)b * H_ + t] = hn;
    out_c[(size_t)b * H_ + t] = cn;
    h_bf[(size_t)b * H_ + t]  = f2bf(hn);
}

// ---------------------------------------------------------------------------
extern "C" void kernel_launch(void* const* d_in, const int* in_sizes, int n_in,
                              void* d_out, int out_size, void* d_ws, size_t ws_size,
                              hipStream_t stream)
{
    (void)in_sizes; (void)n_in; (void)out_size; (void)ws_size;

    const int*   tgt    = (const int*)d_in[0];
    const float* hidden = (const float*)d_in[1];
    const float* cell   = (const float*)d_in[2];
    const float* enc    = (const float*)d_in[3];
    const float* emb    = (const float*)d_in[4];
    const float* attn_W = (const float*)d_in[5];
    const float* attn_b = (const float*)d_in[6];
    const float* vv     = (const float*)d_in[7];
    const float* W_ih   = (const float*)d_in[8];
    const float* W_hh   = (const float*)d_in[9];
    const float* b_ih   = (const float*)d_in[10];
    const float* b_hh   = (const float*)d_in[11];
    const float* fc_W   = (const float*)d_in[12];
    const float* fc_b   = (const float*)d_in[13];

    float* out_pred = (float*)d_out;                       // [256][16000]
    float* out_h    = out_pred + (size_t)B_ * V_;          // [256][512]
    float* out_c    = out_h + (size_t)B_ * H_;             // [256][512]
    float* out_attn = out_c + (size_t)B_ * H_;             // [256][512]

    char*  ws      = (char*)d_ws;
    float* bias1   = (float*)ws;                           // 131072 f32
    float* gates   = bias1 + (size_t)B_ * H_;              // 524288 f32
    float* e_ws    = gates + (size_t)B_ * 2048;            // 131072 f32
    float* lpart   = e_ws + (size_t)B_ * S_;               // 512 f32
    float* ctxpart = lpart + 512;                          // 262144 f32
    short* x_cat   = (short*)(ctxpart + (size_t)512 * H_); // 327680 bf16
    short* h_bf    = x_cat + (size_t)B_ * 1280;            // 131072 bf16
    unsigned* b2p  = (unsigned*)(h_bf + (size_t)B_ * H_);  // 65536 dwords (fp8 x 262144)

    // 0. pack W2 half into fragment-ordered fp8 (x64)
    pack_w2<<<128, 256, 0, stream>>>(attn_W, b2p);
    // 1. embedding gather + h into x_cat (bf16)
    prep_kernel<<<B_, 256, 0, stream>>>(tgt, emb, hidden, x_cat);
    // 2. bias1 = h @ W1^T + attn_b
    bias1_kernel<<<128, 512, 0, stream>>>(hidden, attn_W, attn_b, bias1);
    // 3. fused attention partials: 2 blocks per batch (half-S each)
    fused_attn<<<2 * B_, 512, 0, stream>>>(enc, b2p, bias1, vv, e_ws, lpart, ctxpart);
    // 4. combine partials -> attn out + ctx slice of x_cat
    combine_kernel<<<B_, 512, 0, stream>>>(e_ws, lpart, ctxpart, out_attn, x_cat);
    // 5. gates = x_cat @ [W_ih|W_hh]^T + b_ih + b_hh
    gemm_std<0><<<dim3(2, 16), 256, 0, stream>>>(x_cat, W_ih, W_hh, b_ih, b_hh, gates);
    // 6. LSTM pointwise
    lstm_kernel<<<B_, 512, 0, stream>>>(gates, cell, out_h, out_c, h_bf);
    // 7. prediction = h_new @ fc_W^T + fc_b
    gemm_std<1><<<dim3(2, 125), 256, 0, stream>>>(h_bf, fc_W, nullptr, fc_b, nullptr, out_pred);
}

// Round 8
// 264.386 us; speedup vs baseline: 1.1704x; 1.1704x over previous
//
#include <hip/hip_runtime.h>
#include <hip/hip_bf16.h>

// DecoderLSTM: B=256, S=512, H=512, E=256, V=16000
#define B_ 256
#define S_ 512
#define H_ 512
#define E_ 256
#define V_ 16000

typedef __attribute__((ext_vector_type(4))) float f32x4_t;
typedef __attribute__((ext_vector_type(2))) float f32x2_t;
typedef __attribute__((ext_vector_type(8))) short bf16x8_t;
typedef __attribute__((ext_vector_type(2))) unsigned u32x2_t;

#define W2_SCALE 64.0f
#define W2_INV   0.015625f

__device__ __forceinline__ short f2bf(float f) {
    union { float f; unsigned u; } v; v.f = f;
    unsigned r = v.u + 0x7fffu + ((v.u >> 16) & 1u);   // RNE
    return (short)(r >> 16);
}

__device__ __forceinline__ float bf2f(short s) {
    union { unsigned u; float f; } v; v.u = ((unsigned)(unsigned short)s) << 16;
    return v.f;
}

__device__ __forceinline__ void cvt8(short* dst, const float* src) {
    f32x4_t a = *(const f32x4_t*)src;
    f32x4_t b = *(const f32x4_t*)(src + 4);
    bf16x8_t o;
    o[0] = f2bf(a[0]); o[1] = f2bf(a[1]); o[2] = f2bf(a[2]); o[3] = f2bf(a[3]);
    o[4] = f2bf(b[0]); o[5] = f2bf(b[1]); o[6] = f2bf(b[2]); o[7] = f2bf(b[3]);
    *(bf16x8_t*)dst = o;
}

__device__ __forceinline__ bf16x8_t pack8(f32x4_t a, f32x4_t b) {
    bf16x8_t o;
    o[0] = f2bf(a[0]); o[1] = f2bf(a[1]); o[2] = f2bf(a[2]); o[3] = f2bf(a[3]);
    o[4] = f2bf(b[0]); o[5] = f2bf(b[1]); o[6] = f2bf(b[2]); o[7] = f2bf(b[3]);
    return o;
}

// 8 fp8(e4m3) packed in 2 dwords -> bf16x8
__device__ __forceinline__ bf16x8_t fp8x8_to_bf16x8(u32x2_t r) {
    f32x2_t f0 = __builtin_amdgcn_cvt_pk_f32_fp8(r[0], false);
    f32x2_t f1 = __builtin_amdgcn_cvt_pk_f32_fp8(r[0], true);
    f32x2_t f2 = __builtin_amdgcn_cvt_pk_f32_fp8(r[1], false);
    f32x2_t f3 = __builtin_amdgcn_cvt_pk_f32_fp8(r[1], true);
    union { unsigned u[4]; bf16x8_t v; } o;
    { float a = f0[0], b = f0[1]; asm("v_cvt_pk_bf16_f32 %0, %1, %2" : "=v"(o.u[0]) : "v"(a), "v"(b)); }
    { float a = f1[0], b = f1[1]; asm("v_cvt_pk_bf16_f32 %0, %1, %2" : "=v"(o.u[1]) : "v"(a), "v"(b)); }
    { float a = f2[0], b = f2[1]; asm("v_cvt_pk_bf16_f32 %0, %1, %2" : "=v"(o.u[2]) : "v"(a), "v"(b)); }
    { float a = f3[0], b = f3[1]; asm("v_cvt_pk_bf16_f32 %0, %1, %2" : "=v"(o.u[3]) : "v"(a), "v"(b)); }
    return o.v;
}

__device__ __forceinline__ float fast_tanh(float x) {
    float xc = fminf(8.f, fmaxf(-8.f, x));
    float e = __expf(2.f * xc);
    return (e - 1.f) / (e + 1.f);
}

// LDS chunk swizzle: row has 64 16B-chunks; interleave chunk bits + XOR row.
__device__ __forceinline__ int physc(int c, int r) {
    return ((((c & 7) << 3) | (c >> 3)) ^ (r & 7));
}

// ---------------------------------------------------------------------------
// pack_w2: attn_W second half (W2), scaled x64 -> fragment-ordered FP8 e4m3,
// 16-wave layout: chunk c = ((kk*16 + w)*2 + nf)*64 + lane holds 8 fp8 of
//   W2[col = w*32+nf*16+(lane&15)][k = kk*32+(lane>>4)*8 + j] * 64
// ---------------------------------------------------------------------------
__global__ void pack_w2(const float* __restrict__ attn_W, unsigned* __restrict__ Bp)
{
    const int c    = blockIdx.x * 256 + threadIdx.x;       // 32768 chunks
    const int lane = c & 63;
    const int nf   = (c >> 6) & 1;
    const int w    = (c >> 7) & 15;
    const int kk   = c >> 11;                              // 0..15
    const int col  = w * 32 + nf * 16 + (lane & 15);
    const int k    = kk * 32 + (lane >> 4) * 8;
    const float* src = attn_W + (size_t)col * (2 * H_) + H_ + k;
    f32x4_t a = *(const f32x4_t*)src;
    f32x4_t b = *(const f32x4_t*)(src + 4);
    unsigned lo = 0, hi = 0;
    lo = __builtin_amdgcn_cvt_pk_fp8_f32(a[0] * W2_SCALE, a[1] * W2_SCALE, lo, false);
    lo = __builtin_amdgcn_cvt_pk_fp8_f32(a[2] * W2_SCALE, a[3] * W2_SCALE, lo, true);
    hi = __builtin_amdgcn_cvt_pk_fp8_f32(b[0] * W2_SCALE, b[1] * W2_SCALE, hi, false);
    hi = __builtin_amdgcn_cvt_pk_fp8_f32(b[2] * W2_SCALE, b[3] * W2_SCALE, hi, true);
    u32x2_t st; st[0] = lo; st[1] = hi;
    *(u32x2_t*)(Bp + (size_t)c * 2) = st;
}

// ---------------------------------------------------------------------------
// bias1: h @ W1^T + attn_b.  128 blocks x 512 thr, 2 batches per block.
// ---------------------------------------------------------------------------
__global__ void bias1_kernel(const float* __restrict__ hidden,
                             const float* __restrict__ attn_W,
                             const float* __restrict__ attn_b,
                             float* __restrict__ bias1)
{
    const int t  = threadIdx.x;                // output col
    const int b0 = blockIdx.x * 2;
    __shared__ float h_s[2][512];
    h_s[0][t] = hidden[(size_t)b0 * H_ + t];
    h_s[1][t] = hidden[(size_t)(b0 + 1) * H_ + t];
    __syncthreads();
    const float* wrow = attn_W + (size_t)t * (2 * H_);     // W1 part: cols 0..511
    float a0 = 0.f, a1 = 0.f;
#pragma unroll 4
    for (int k = 0; k < 512; k += 4) {
        f32x4_t wv = *(const f32x4_t*)(wrow + k);
        a0 = fmaf(wv[0], h_s[0][k],     a0);
        a0 = fmaf(wv[1], h_s[0][k + 1], a0);
        a0 = fmaf(wv[2], h_s[0][k + 2], a0);
        a0 = fmaf(wv[3], h_s[0][k + 3], a0);
        a1 = fmaf(wv[0], h_s[1][k],     a1);
        a1 = fmaf(wv[1], h_s[1][k + 1], a1);
        a1 = fmaf(wv[2], h_s[1][k + 2], a1);
        a1 = fmaf(wv[3], h_s[1][k + 3], a1);
    }
    const float bb = attn_b[t];
    bias1[(size_t)b0 * H_ + t]       = a0 + bb;
    bias1[(size_t)(b0 + 1) * H_ + t] = a1 + bb;
}

// ---------------------------------------------------------------------------
// fused_attn: 256 blocks x 1024 threads (16 waves). One full batch per block.
// The 1024-thread block is the occupancy mechanism: 16 waves are atomic ->
// 4 waves/SIMD co-resident by construction, and the backend must cap VGPR at
// 128 to schedule it (no launch_bounds/waves_per_eu attribute games - those
// unpredictably squeezed to 64 VGPR and spilled in rounds 4/5/7).
// Double-buffered 2x64KB LDS: per tile, stage(tile+1) -> GEMM(tile) ->
// tanh+v reduce -> e=exp(score) -> ctx accumulate, 3 barriers. Wave owns
// 64 rows x 32 cols (acc[4][2] = 32 VGPR). B = fp8 e4m3 (x64) fragments,
// converted in-register (halves B L2 bytes). |score|<=22.6 -> plain exp,
// no max subtraction; full-S block -> attn + ctx finalized in-kernel.
// ---------------------------------------------------------------------------
__global__ __launch_bounds__(1024)
void fused_attn(const float* __restrict__ enc,
                const unsigned* __restrict__ Bp,
                const float* __restrict__ bias1,
                const float* __restrict__ vvec,
                float* __restrict__ out_attn,
                short* __restrict__ x_cat)
{
    __shared__ short buf[2][64 * 512];       // 2 x 64 KB, swizzled chunks
    __shared__ float bias_s[512];
    __shared__ float v_s[512];
    __shared__ float e_all[512];
    __shared__ float red[64][17];
    __shared__ float ctx_s[512];
    __shared__ float wred[8];
    __shared__ float l_sh;

    const int t    = threadIdx.x;
    const int lane = t & 63;
    const int w    = t >> 6;                 // 0..15, col group (32 cols)
    const int b    = blockIdx.x;

    if (t < 512) {
        bias_s[t] = bias1[(size_t)b * H_ + t];
        v_s[t]    = vvec[t];
    }

    // staging: row srow (0..63), slot sc (0..15) -> chunks sc + i*16, i=0..3
    const int srow = t >> 4;
    const int sc   = t & 15;
    const float* gbase = enc + ((size_t)b * S_ + srow) * H_ + sc * 8;

    // ctx: chunk cc = t>>4 (0..63), row residue rg = t&15 (rows rg + 16i)
    const int cc = t >> 4;
    const int rg = t & 15;
    float acc8[8];
#pragma unroll
    for (int j = 0; j < 8; ++j) acc8[j] = 0.f;

    // prologue: stage tile 0 into buf[0]
#pragma unroll
    for (int i = 0; i < 4; ++i) {
        const float* sp = gbase + i * 16 * 8;
        f32x4_t a = *(const f32x4_t*)(sp);
        f32x4_t c = *(const f32x4_t*)(sp + 4);
        *(bf16x8_t*)&buf[0][srow * 512 + physc(sc + i * 16, srow) * 8] = pack8(a, c);
    }
    __syncthreads();

    int cur = 0;
    for (int tile = 0; tile < 8; ++tile) {
        // ---- stage tile+1 into buf[cur^1] (last read 1 barrier-epoch ago)
        if (tile < 7) {
            const float* gp = gbase + (size_t)(tile + 1) * 64 * H_;
#pragma unroll
            for (int i = 0; i < 4; ++i) {
                const float* sp = gp + i * 16 * 8;
                f32x4_t a = *(const f32x4_t*)(sp);
                f32x4_t c = *(const f32x4_t*)(sp + 4);
                *(bf16x8_t*)&buf[cur ^ 1][srow * 512 + physc(sc + i * 16, srow) * 8] = pack8(a, c);
            }
        }

        // ---- energy GEMM on buf[cur]: 64 rows x 32 cols (this wave) x K=512
        const short* bufc = buf[cur];
        f32x4_t acc[4][2];
#pragma unroll
        for (int mf = 0; mf < 4; ++mf) {
            acc[mf][0] = (f32x4_t){0.f, 0.f, 0.f, 0.f};
            acc[mf][1] = (f32x4_t){0.f, 0.f, 0.f, 0.f};
        }

#pragma unroll 4
        for (int kk = 0; kk < 16; ++kk) {
            const unsigned* bb = Bp + ((size_t)((kk * 16 + w) * 2) * 64 + lane) * 2;
            u32x2_t braw0 = *(const u32x2_t*)(bb);
            u32x2_t braw1 = *(const u32x2_t*)(bb + 128);
            bf16x8_t af[4];
            const int cpr = kk * 4 + (lane >> 4);
#pragma unroll
            for (int mf = 0; mf < 4; ++mf) {
                const int rl = mf * 16 + (lane & 15);
                af[mf] = *(const bf16x8_t*)&bufc[rl * 512 + physc(cpr, rl) * 8];
            }
            bf16x8_t bfr0 = fp8x8_to_bf16x8(braw0);
            bf16x8_t bfr1 = fp8x8_to_bf16x8(braw1);
            __builtin_amdgcn_s_setprio(1);
#pragma unroll
            for (int mf = 0; mf < 4; ++mf) {
                acc[mf][0] = __builtin_amdgcn_mfma_f32_16x16x32_bf16(af[mf], bfr0, acc[mf][0], 0, 0, 0);
                acc[mf][1] = __builtin_amdgcn_mfma_f32_16x16x32_bf16(af[mf], bfr1, acc[mf][1], 0, 0, 0);
            }
            __builtin_amdgcn_s_setprio(0);
        }

        // ---- epilogue: per-wave partial score over its 32 cols
        float part[16];
#pragma unroll
        for (int i = 0; i < 16; ++i) part[i] = 0.f;
#pragma unroll
        for (int nf = 0; nf < 2; ++nf) {
            const int col = w * 32 + nf * 16 + (lane & 15);
            const float bbv = bias_s[col];
            const float vl  = v_s[col];
#pragma unroll
            for (int mf = 0; mf < 4; ++mf)
#pragma unroll
                for (int r = 0; r < 4; ++r)
                    part[mf * 4 + r] += vl * fast_tanh(fmaf(acc[mf][nf][r], W2_INV, bbv));
        }
#pragma unroll
        for (int i = 0; i < 16; ++i) {
            float p = part[i];
            p += __shfl_xor(p, 1);
            p += __shfl_xor(p, 2);
            p += __shfl_xor(p, 4);
            p += __shfl_xor(p, 8);
            part[i] = p;
        }
        if ((lane & 15) == 0) {
#pragma unroll
            for (int mf = 0; mf < 4; ++mf)
#pragma unroll
                for (int r = 0; r < 4; ++r)
                    red[mf * 16 + ((lane >> 4) << 2) + r][w] = part[mf * 4 + r];
        }
        __syncthreads();                      // B1: red + staging writes done

        if (t < 64) {
            float s = 0.f;
#pragma unroll
            for (int g = 0; g < 16; ++g) s += red[t][g];
            e_all[tile * 64 + t] = __expf(s);
        }
        __syncthreads();                      // B2: e_all visible

        // ---- context accumulate from bufc: rows rg+16i, chunk cc
#pragma unroll
        for (int i = 0; i < 4; ++i) {
            const int r   = i * 16 + rg;
            const float e = e_all[tile * 64 + r];
            bf16x8_t ch = *(const bf16x8_t*)&bufc[r * 512 + physc(cc, r) * 8];
#pragma unroll
            for (int j = 0; j < 8; ++j)
                acc8[j] = fmaf(e, bf2f(ch[j]), acc8[j]);
        }
        __syncthreads();                      // B3: ctx reads done (next stage overwrites)
        cur ^= 1;
    }

    // ---- finalize: reduce ctx over the 16 threads sharing chunk cc
    // (threads cc*16+rg are 16 consecutive lanes of one wave)
#pragma unroll
    for (int m = 1; m < 16; m <<= 1)
#pragma unroll
        for (int j = 0; j < 8; ++j)
            acc8[j] += __shfl_xor(acc8[j], m);
#pragma unroll
    for (int j = 0; j < 8; ++j)
        if (rg == j) ctx_s[cc * 8 + j] = acc8[j];

    // l = sum(e_all)
    if (t < 512) {
        float sv = e_all[t];
#pragma unroll
        for (int off = 32; off; off >>= 1) sv += __shfl_xor(sv, off);
        if (lane == 0) wred[w] = sv;
    }
    __syncthreads();
    if (t == 0) {
        l_sh = wred[0] + wred[1] + wred[2] + wred[3]
             + wred[4] + wred[5] + wred[6] + wred[7];
    }
    __syncthreads();
    if (t < 512) {
        const float li = 1.f / l_sh;
        out_attn[(size_t)b * S_ + t] = e_all[t] * li;
        x_cat[(size_t)b * 1280 + 256 + t] = f2bf(ctx_s[t] * li);
    }
}

// ---------------------------------------------------------------------------
// gemm_std: BM=128, BN=128, BK=32, 4 waves (256 thr). A is pre-converted bf16.
// KIND 0 (gates): K=1280, N=2048, B = [W_ih | W_hh] rows, bias = b_ih+b_hh
// KIND 1 (pred):  K=512,  N=16000, B = fc_W rows,        bias = fc_b
// ---------------------------------------------------------------------------
template<int KIND>
__global__ __launch_bounds__(256, 2)
void gemm_std(const short* __restrict__ Abf,
              const float* __restrict__ B0,
              const float* __restrict__ B1,
              const float* __restrict__ bias0,
              const float* __restrict__ bias1v,
              float* __restrict__ out)
{
    constexpr int K = (KIND == 0) ? 1280 : 512;
    constexpr int N = (KIND == 0) ? 2048 : 16000;

    __shared__ short As[128 * 40];
    __shared__ short Bs[128 * 40];

    const int t    = threadIdx.x;
    const int lane = t & 63;
    const int w    = t >> 6;
    const int wm   = w >> 1;
    const int wn   = w & 1;
    const int row0 = blockIdx.x * 128;
    const int col0 = blockIdx.y * 128;

    f32x4_t acc[4][4];
#pragma unroll
    for (int i = 0; i < 4; ++i)
#pragma unroll
        for (int j = 0; j < 4; ++j)
            acc[i][j] = (f32x4_t){0.f, 0.f, 0.f, 0.f};

    const int arow = t >> 1, ah = (t & 1) * 16;
    const int bcol = t >> 1, bh = (t & 1) * 16;

    for (int ks = 0; ks < K / 32; ++ks) {
        const int k0 = ks * 32;
        __syncthreads();
        const short* asrc = Abf + (size_t)(row0 + arow) * K + k0 + ah;
        *(bf16x8_t*)&As[arow * 40 + ah]     = *(const bf16x8_t*)asrc;
        *(bf16x8_t*)&As[arow * 40 + ah + 8] = *(const bf16x8_t*)(asrc + 8);
        const float* bsrc;
        if constexpr (KIND == 0) {
            const int cg = col0 + bcol;
            bsrc = (k0 < 768) ? (B0 + (size_t)cg * 768 + k0 + bh)
                              : (B1 + (size_t)cg * 512 + (k0 - 768) + bh);
        } else {
            bsrc = B0 + (size_t)(col0 + bcol) * 512 + k0 + bh;
        }
        cvt8(&Bs[bcol * 40 + bh],     bsrc);
        cvt8(&Bs[bcol * 40 + bh + 8], bsrc + 8);
        __syncthreads();

        bf16x8_t af[4], bfr[4];
        const int ka = (lane >> 4) * 8;
#pragma unroll
        for (int mf = 0; mf < 4; ++mf)
            af[mf] = *(const bf16x8_t*)&As[(wm * 64 + mf * 16 + (lane & 15)) * 40 + ka];
#pragma unroll
        for (int nf = 0; nf < 4; ++nf)
            bfr[nf] = *(const bf16x8_t*)&Bs[(wn * 64 + nf * 16 + (lane & 15)) * 40 + ka];
#pragma unroll
        for (int mf = 0; mf < 4; ++mf)
#pragma unroll
            for (int nf = 0; nf < 4; ++nf)
                acc[mf][nf] = __builtin_amdgcn_mfma_f32_16x16x32_bf16(
                    af[mf], bfr[nf], acc[mf][nf], 0, 0, 0);
    }

#pragma unroll
    for (int mf = 0; mf < 4; ++mf)
#pragma unroll
        for (int nf = 0; nf < 4; ++nf) {
            const int col  = col0 + wn * 64 + nf * 16 + (lane & 15);
            const int rowb = row0 + wm * 64 + mf * 16 + ((lane >> 4) << 2);
            float bb;
            if constexpr (KIND == 0) bb = bias0[col] + bias1v[col];
            else                     bb = bias0[col];
#pragma unroll
            for (int r = 0; r < 4; ++r)
                out[(size_t)(rowb + r) * N + col] = acc[mf][nf][r] + bb;
        }
}

// ---------------------------------------------------------------------------
// small kernels
// ---------------------------------------------------------------------------
__global__ void prep_kernel(const int* __restrict__ tgt,
                            const float* __restrict__ emb,
                            const float* __restrict__ hidden,
                            short* __restrict__ x_cat)
{
    const int b = blockIdx.x, t = threadIdx.x;          // 256 threads
    const int tok = tgt[b];
    x_cat[(size_t)b * 1280 + t]             = f2bf(emb[(size_t)tok * E_ + t]);
    x_cat[(size_t)b * 1280 + 768 + t]       = f2bf(hidden[(size_t)b * H_ + t]);
    x_cat[(size_t)b * 1280 + 768 + 256 + t] = f2bf(hidden[(size_t)b * H_ + 256 + t]);
}

__global__ void lstm_kernel(const float* __restrict__ gates,
                            const float* __restrict__ cell,
                            float* __restrict__ out_h,
                            float* __restrict__ out_c,
                            short* __restrict__ h_bf)
{
    const int b = blockIdx.x, t = threadIdx.x;          // 512 threads
    const float* g = gates + (size_t)b * 2048;
    const float gi = g[t], gf = g[512 + t], gg = g[1024 + t], go = g[1536 + t];
    const float c  = cell[(size_t)b * H_ + t];
    const float si = 1.f / (1.f + __expf(-gi));
    const float sf = 1.f / (1.f + __expf(-gf));
    const float so = 1.f / (1.f + __expf(-go));
    const float cn = sf * c + si * tanhf(gg);
    const float hn = so * tanhf(cn);
    out_h[(size_t)b * H_ + t] = hn;
    out_c[(size_t)b * H_ + t] = cn;
    h_bf[(size_t)b * H_ + t]  = f2bf(hn);
}

// ---------------------------------------------------------------------------
extern "C" void kernel_launch(void* const* d_in, const int* in_sizes, int n_in,
                              void* d_out, int out_size, void* d_ws, size_t ws_size,
                              hipStream_t stream)
{
    (void)in_sizes; (void)n_in; (void)out_size; (void)ws_size;

    const int*   tgt    = (const int*)d_in[0];
    const float* hidden = (const float*)d_in[1];
    const float* cell   = (const float*)d_in[2];
    const float* enc    = (const float*)d_in[3];
    const float* emb    = (const float*)d_in[4];
    const float* attn_W = (const float*)d_in[5];
    const float* attn_b = (const float*)d_in[6];
    const float* vv     = (const float*)d_in[7];
    const float* W_ih   = (const float*)d_in[8];
    const float* W_hh   = (const float*)d_in[9];
    const float* b_ih   = (const float*)d_in[10];
    const float* b_hh   = (const float*)d_in[11];
    const float* fc_W   = (const float*)d_in[12];
    const float* fc_b   = (const float*)d_in[13];

    float* out_pred = (float*)d_out;                       // [256][16000]
    float* out_h    = out_pred + (size_t)B_ * V_;          // [256][512]
    float* out_c    = out_h + (size_t)B_ * H_;             // [256][512]
    float* out_attn = out_c + (size_t)B_ * H_;             // [256][512]

    char*  ws      = (char*)d_ws;
    float* bias1   = (float*)ws;                           // 131072 f32
    float* gates   = bias1 + (size_t)B_ * H_;              // 524288 f32
    short* x_cat   = (short*)(gates + (size_t)B_ * 2048);  // 327680 bf16
    short* h_bf    = x_cat + (size_t)B_ * 1280;            // 131072 bf16
    unsigned* b2p  = (unsigned*)(h_bf + (size_t)B_ * H_);  // 65536 dwords (fp8 x 262144)

    // 0. pack W2 half into fragment-ordered fp8 (x64)
    pack_w2<<<128, 256, 0, stream>>>(attn_W, b2p);
    // 1. embedding gather + h into x_cat (bf16)
    prep_kernel<<<B_, 256, 0, stream>>>(tgt, emb, hidden, x_cat);
    // 2. bias1 = h @ W1^T + attn_b
    bias1_kernel<<<128, 512, 0, stream>>>(hidden, attn_W, attn_b, bias1);
    // 3. fused attention: scores + softmax + context, enc read once
    fused_attn<<<B_, 1024, 0, stream>>>(enc, b2p, bias1, vv, out_attn, x_cat);
    // 4. gates = x_cat @ [W_ih|W_hh]^T + b_ih + b_hh
    gemm_std<0><<<dim3(2, 16), 256, 0, stream>>>(x_cat, W_ih, W_hh, b_ih, b_hh, gates);
    // 5. LSTM pointwise
    lstm_kernel<<<B_, 512, 0, stream>>>(gates, cell, out_h, out_c, h_bf);
    // 6. prediction = h_new @ fc_W^T + fc_b
    gemm_std<1><<<dim3(2, 125), 256, 0, stream>>>(h_bf, fc_W, nullptr, fc_b, nullptr, out_pred);
}